// Round 10
// baseline (1083.006 us; speedup 1.0000x reference)
//
#include <hip/hip_runtime.h>
#include <math.h>

#define NN 50000
#define NE 800000
#define GG 50

typedef unsigned int u32;
typedef unsigned short u16;
typedef float v2f __attribute__((ext_vector_type(2)));
typedef short bf16x8 __attribute__((ext_vector_type(8)));
typedef float f32x4 __attribute__((ext_vector_type(4)));

__device__ __forceinline__ float uaf(u32 x) { return __uint_as_float(x); }

__device__ __forceinline__ u32 bfpack2(float x, float y) {
    u32 a = __float_as_uint(x), b = __float_as_uint(y);
    a = (a + 0x7fffu + ((a >> 16) & 1u)) >> 16;
    b = (b + 0x7fffu + ((b >> 16) & 1u)) & 0xffff0000u;
    return b | a;
}
__device__ __forceinline__ u16 bf16of(float x) {
    u32 a = __float_as_uint(x);
    return (u16)((a + 0x7fffu + ((a >> 16) & 1u)) >> 16);
}

template <int CTRL>
__device__ __forceinline__ float dpp_add(float v) {
    int t = __builtin_amdgcn_update_dpp(0, __float_as_int(v), CTRL, 0xf, 0xf, true);
    return v + __int_as_float(t);
}
__device__ __forceinline__ float swz_xor16_add(float v) {
    int t = __builtin_amdgcn_ds_swizzle(__float_as_int(v), 0x401F);
    return v + __int_as_float(t);
}
__device__ __forceinline__ float total64(float v) {
    return __int_as_float(__builtin_amdgcn_readlane(__float_as_int(v), 0))
         + __int_as_float(__builtin_amdgcn_readlane(__float_as_int(v), 32));
}
#define RED4_STAGES(q)  do {                                                    \
    _Pragma("unroll") for (int j = 0; j < 4; ++j) q[j] = dpp_add<0xB1>(q[j]);  \
    _Pragma("unroll") for (int j = 0; j < 4; ++j) q[j] = dpp_add<0x4E>(q[j]);  \
    _Pragma("unroll") for (int j = 0; j < 4; ++j) q[j] = dpp_add<0x141>(q[j]); \
    _Pragma("unroll") for (int j = 0; j < 4; ++j) q[j] = dpp_add<0x140>(q[j]); \
} while (0)

// ---------------- mega pre-kernel: zeros + ea pack + x pack + weight packs ----------------
#define PRE_ZERO 100384
#define PRE_EA   (PRE_ZERO + 6400000)
#define PRE_XP   (PRE_EA + 3200000)
#define PRE_W1   (PRE_XP + 24576)
#define PRE_W2   (PRE_W1 + 12288)
#define PRE_TOT  PRE_W2

__device__ __forceinline__ void wpack_item(const float* __restrict__ W0, const float* __restrict__ W1,
                                           const float* __restrict__ W2, u32* __restrict__ Wt, int M, int j) {
    int per = M * 64;
    int mat = j / per;
    int r = j - mat * per;
    const float* W = (mat == 0) ? W0 : (mat == 1) ? W1 : W2;
    int col = r >> 6, c = r & 63;
    Wt[j] = bfpack2(W[(size_t)(2 * c) * M + col], W[(size_t)(2 * c + 1) * M + col]);
}

__global__ __launch_bounds__(256) void pre_kernel(
    const float* __restrict__ ea, const float* __restrict__ x,
    const float* __restrict__ w1a, const float* __restrict__ w1b, const float* __restrict__ w1c,
    const float* __restrict__ w2a, const float* __restrict__ w2b, const float* __restrict__ w2c,
    u32* __restrict__ zbase, u32* __restrict__ eah, u32* __restrict__ xp,
    u32* __restrict__ wt1, u32* __restrict__ wt2)
{
    int i = blockIdx.x * 256 + threadIdx.x;
    if (i < PRE_ZERO) {
        zbase[i] = 0u;
    } else if (i < PRE_EA) {
        int j = i - PRE_ZERO;
        float2 v = *(const float2*)(ea + (size_t)j * 2);
        eah[j] = bfpack2(v.x, v.y);
    } else if (i < PRE_XP) {
        int j = i - PRE_EA;
        float2 v = *(const float2*)(x + (size_t)j * 2);
        xp[j] = bfpack2(v.x, v.y);
    } else if (i < PRE_W1) {
        wpack_item(w1a, w1b, w1c, wt1, 128, i - PRE_XP);
    } else if (i < PRE_W2) {
        wpack_item(w2a, w2b, w2c, wt2, 64, i - PRE_W1);
    }
}

// ---------------- CSR: count ----------------
__global__ void count_edges_kernel(const int* __restrict__ ei, u32* __restrict__ counts) {
    int e = blockIdx.x * 256 + threadIdx.x;
    if (e < NE) atomicAdd(&counts[ei[NE + e]], 1u);
}

// ---------------- CSR: single-block full scan (replaces 3 kernels) ----------------
__global__ __launch_bounds__(1024) void scan_kernel(const u32* __restrict__ counts, int* __restrict__ rowptr) {
    __shared__ u32 ts[1024];
    int t = threadIdx.x;
    int base = t * 49;
    u32 c[49];
    u32 s = 0;
#pragma unroll
    for (int j = 0; j < 49; ++j) {
        int idx = base + j;
        c[j] = (idx < NN) ? counts[idx] : 0u;
        s += c[j];
    }
    ts[t] = s;
    __syncthreads();
    for (int off = 1; off < 1024; off <<= 1) {
        u32 add = (t >= off) ? ts[t - off] : 0u;
        __syncthreads();
        ts[t] += add;
        __syncthreads();
    }
    u32 run = ts[t] - s;
#pragma unroll
    for (int j = 0; j < 49; ++j) {
        int idx = base + j;
        if (idx < NN) rowptr[idx] = (int)run;
        run += c[j];
    }
    if (t == 1023) rowptr[NN] = NE;
}

// ---------------- merged: scatter (blocks 0..3124) + layer-1 MFMA GEMM (rest) ----------------
__global__ __launch_bounds__(256) void scatter_gemm1_kernel(
    const int* __restrict__ ei, const int* __restrict__ rowptr,
    u32* __restrict__ cursors, int2* __restrict__ pairs,
    const u32* __restrict__ Xp, const u32* __restrict__ Wt,
    u16* __restrict__ out0, float* __restrict__ out1, float* __restrict__ out2,
    const float* __restrict__ b0, const float* __restrict__ b1, const float* __restrict__ b2)
{
    __shared__ __align__(16) u32 Xs[64 * 68];
    __shared__ __align__(16) u32 Ws[64 * 68];
    int t = threadIdx.x;

    if (blockIdx.x < 3125) {                       // scatter part
        int e = blockIdx.x * 256 + t;
        if (e < NE) {
            int src = ei[e];
            int d = ei[NE + e];
            u32 pos = atomicAdd(&cursors[d], 1u);
            pairs[rowptr[d] + pos] = make_int2(src, e);
        }
        return;
    }
    int bid = blockIdx.x - 3125;                   // gemm part: 782*6 blocks
    int nb = bid / 782;
    int rowb = bid - nb * 782;
    int row0 = rowb * 64;
    int mat = nb >> 1;                             // nbPerMat = 2
    int col0 = (nb & 1) * 64;
    int gcol0 = nb * 64;

#pragma unroll
    for (int i = 0; i < 16; ++i) {
        int flat = t + 256 * i;
        int r = flat >> 6, c = flat & 63;
        int gr = row0 + r;
        u32 v = (gr < NN) ? Xp[(size_t)gr * 64 + c] : 0u;
        Xs[r * 68 + c] = v;
    }
#pragma unroll
    for (int i = 0; i < 16; ++i) {
        int flat = t + 256 * i;
        int cc = flat >> 6, c = flat & 63;
        Ws[cc * 68 + c] = Wt[(size_t)(gcol0 + cc) * 64 + c];
    }
    __syncthreads();

    int w = t >> 6, lane = t & 63;
    int l15 = lane & 15, quad = lane >> 4;
    f32x4 acc[4] = {};
#pragma unroll
    for (int kk = 0; kk < 4; ++kk) {
        bf16x8 af = *(const bf16x8*)&Xs[(w * 16 + l15) * 68 + kk * 16 + quad * 4];
#pragma unroll
        for (int j = 0; j < 4; ++j) {
            bf16x8 bf = *(const bf16x8*)&Ws[(j * 16 + l15) * 68 + kk * 16 + quad * 4];
            acc[j] = __builtin_amdgcn_mfma_f32_16x16x32_bf16(af, bf, acc[j], 0, 0, 0);
        }
    }
    const float* bp = (mat == 0) ? b0 : (mat == 1) ? b1 : b2;
#pragma unroll
    for (int j = 0; j < 4; ++j) {
        int col = col0 + j * 16 + l15;
        float bb = bp[col];
#pragma unroll
        for (int r = 0; r < 4; ++r) {
            int grow = row0 + w * 16 + quad * 4 + r;
            if (grow < NN) {
                float v = acc[j][r] + bb;
                if (mat == 0)      out0[(size_t)grow * 128 + col] = bf16of(v);
                else if (mat == 1) out1[(size_t)grow * 128 + col] = v;
                else               out2[(size_t)grow * 128 + col] = v;
            }
        }
    }
}

// ---------------- layer-2 MFMA GEMM (standalone) ----------------
__global__ __launch_bounds__(256) void gemm_mfma_kernel(
    const u32* __restrict__ Xp, const u32* __restrict__ Wt,
    u16* __restrict__ out0, float* __restrict__ out1, float* __restrict__ out2,
    const float* __restrict__ b0, const float* __restrict__ b1, const float* __restrict__ b2)
{
    __shared__ __align__(16) u32 Xs[64 * 68];
    __shared__ __align__(16) u32 Ws[64 * 68];
    int t = threadIdx.x;
    int row0 = blockIdx.x * 64;
    int nb = blockIdx.y;          // 0..2, nbPerMat = 1, M = 64
    int mat = nb;
    int gcol0 = nb * 64;

#pragma unroll
    for (int i = 0; i < 16; ++i) {
        int flat = t + 256 * i;
        int r = flat >> 6, c = flat & 63;
        int gr = row0 + r;
        u32 v = (gr < NN) ? Xp[(size_t)gr * 64 + c] : 0u;
        Xs[r * 68 + c] = v;
    }
#pragma unroll
    for (int i = 0; i < 16; ++i) {
        int flat = t + 256 * i;
        int cc = flat >> 6, c = flat & 63;
        Ws[cc * 68 + c] = Wt[(size_t)(gcol0 + cc) * 64 + c];
    }
    __syncthreads();

    int w = t >> 6, lane = t & 63;
    int l15 = lane & 15, quad = lane >> 4;
    f32x4 acc[4] = {};
#pragma unroll
    for (int kk = 0; kk < 4; ++kk) {
        bf16x8 af = *(const bf16x8*)&Xs[(w * 16 + l15) * 68 + kk * 16 + quad * 4];
#pragma unroll
        for (int j = 0; j < 4; ++j) {
            bf16x8 bf = *(const bf16x8*)&Ws[(j * 16 + l15) * 68 + kk * 16 + quad * 4];
            acc[j] = __builtin_amdgcn_mfma_f32_16x16x32_bf16(af, bf, acc[j], 0, 0, 0);
        }
    }
    const float* bp = (mat == 0) ? b0 : (mat == 1) ? b1 : b2;
#pragma unroll
    for (int j = 0; j < 4; ++j) {
        int col = j * 16 + l15;
        float bb = bp[col];
#pragma unroll
        for (int r = 0; r < 4; ++r) {
            int grow = row0 + w * 16 + quad * 4 + r;
            if (grow < NN) {
                float v = acc[j][r] + bb;
                if (mat == 0)      out0[(size_t)grow * 64 + col] = bf16of(v);
                else if (mat == 1) out1[(size_t)grow * 64 + col] = v;
                else               out2[(size_t)grow * 64 + col] = v;
            }
        }
    }
}

// ---------------- fused GATv2 layer 1 + BN stats ----------------
__global__ __launch_bounds__(256) void gat1_fused_kernel(
    const u32* __restrict__ xlp, const float* __restrict__ xr,
    const u32* __restrict__ eah, const int2* __restrict__ pairs,
    const int* __restrict__ rowptr, const float* __restrict__ We,
    const float* __restrict__ att, const float* __restrict__ bias,
    float* __restrict__ out, float* __restrict__ stats)
{
    __shared__ float sred[4][128];
    __shared__ float q2red[4][128];
    int lane = threadIdx.x & 63;
    int d = (blockIdx.x * 256 + threadIdx.x) >> 6;   // grid exactly NN/4 blocks: d < NN always
    int du = __builtin_amdgcn_readfirstlane(d);
    int beg = rowptr[du], end = rowptr[du + 1];
    int c0 = lane * 2;
    v2f w[16];
#pragma unroll
    for (int k = 0; k < 16; ++k) {
        float2 t2 = *(const float2*)(We + k * 128 + c0);
        w[k] = (v2f){t2.x, t2.y};
    }
    float a0 = att[c0], a1 = att[c0 + 1];
    float2 bt = *(const float2*)(bias + c0);
    float2 xq = *(const float2*)(xr + (size_t)du * 128 + c0);
    v2f xrv = {xq.x, xq.y};

    float s = 0.f;
    v2f acc = {0.f, 0.f};

    int cnt = (end - beg) >> 2;
    int2 pA[4]; u32 eA[4][8]; u32 xA[4];
    int2 pB[4]; u32 eB[4][8]; u32 xB[4];

#define G1_LOAD(P, EB, X, base_) do {                                          \
    _Pragma("unroll")                                                          \
    for (int j = 0; j < 4; ++j) P[j] = pairs[(base_) + j];                     \
    _Pragma("unroll")                                                          \
    for (int j = 0; j < 4; ++j) {                                              \
        const u32* er_ = eah + (size_t)P[j].y * 8;                             \
        _Pragma("unroll")                                                      \
        for (int k = 0; k < 8; ++k) EB[j][k] = er_[k];                         \
        X[j] = xlp[(size_t)P[j].x * 64 + lane];                                \
    }                                                                          \
} while (0)

#define G1_PROC(EB, X) do {                                                    \
    float q[4]; v2f xv[4];                                                     \
    _Pragma("unroll")                                                          \
    for (int j = 0; j < 4; ++j) {                                              \
        v2f e = {0.f, 0.f};                                                    \
        _Pragma("unroll")                                                      \
        for (int kk = 0; kk < 8; ++kk) {                                       \
            u32 pk = EB[j][kk];                                                \
            e = w[2 * kk] * uaf(pk << 16) + e;                                 \
            e = w[2 * kk + 1] * uaf(pk & 0xffff0000u) + e;                     \
        }                                                                      \
        u32 px = X[j];                                                         \
        xv[j] = (v2f){uaf(px << 16), uaf(px & 0xffff0000u)};                   \
        v2f mm = xv[j] + xrv + e;                                              \
        float lx = fmaxf(mm.x, 0.2f * mm.x);                                   \
        float ly = fmaxf(mm.y, 0.2f * mm.y);                                   \
        q[j] = fmaf(lx, a0, ly * a1);                                          \
    }                                                                          \
    RED4_STAGES(q);                                                            \
    _Pragma("unroll")                                                          \
    for (int j = 0; j < 4; ++j) q[j] = swz_xor16_add(q[j]);                    \
    float w0 = __expf(q[0]), w1 = __expf(q[1]);                                \
    float w2 = __expf(q[2]), w3 = __expf(q[3]);                                \
    s += (w0 + w1) + (w2 + w3);                                                \
    acc = acc + (xv[0] * w0 + xv[1] * w1) + (xv[2] * w2 + xv[3] * w3);         \
} while (0)

    if (cnt > 0) {
        G1_LOAD(pA, eA, xA, beg);
        int g = 0;
        for (; g + 2 <= cnt; g += 2) {
            G1_LOAD(pB, eB, xB, beg + (g + 1) * 4);
            G1_PROC(eA, xA);
            if (g + 2 < cnt) G1_LOAD(pA, eA, xA, beg + (g + 2) * 4);
            G1_PROC(eB, xB);
        }
        if (g < cnt) G1_PROC(eA, xA);
    }
#undef G1_LOAD
#undef G1_PROC
    for (int i = beg + cnt * 4; i < end; ++i) {
        int2 pr = pairs[i];
        const u32* er = eah + (size_t)pr.y * 8;
        u32 px = xlp[(size_t)pr.x * 64 + lane];
        v2f xv = {uaf(px << 16), uaf(px & 0xffff0000u)};
        v2f e = {0.f, 0.f};
#pragma unroll
        for (int kk = 0; kk < 8; ++kk) {
            u32 pk = er[kk];
            e = w[2 * kk] * uaf(pk << 16) + e;
            e = w[2 * kk + 1] * uaf(pk & 0xffff0000u) + e;
        }
        v2f mm = xv + xrv + e;
        float lx = fmaxf(mm.x, 0.2f * mm.x);
        float ly = fmaxf(mm.y, 0.2f * mm.y);
        float p = fmaf(lx, a0, ly * a1);
        p = dpp_add<0xB1>(p);
        p = dpp_add<0x4E>(p);
        p = dpp_add<0x141>(p);
        p = dpp_add<0x140>(p);
        p = swz_xor16_add(p);
        float ww = __expf(p);
        s += ww;
        acc = acc + xv * ww;
    }
    float inv = 1.f / (s + 1e-16f);
    float2 o;
    o.x = fmaf(acc.x, inv, bt.x);
    o.y = fmaf(acc.y, inv, bt.y);
    *(float2*)(out + (size_t)d * 128 + c0) = o;

    // BN stats: per-block reduce then one atomic per channel
    int wv = threadIdx.x >> 6;
    sred[wv][c0] = o.x;  sred[wv][c0 + 1] = o.y;
    q2red[wv][c0] = o.x * o.x;  q2red[wv][c0 + 1] = o.y * o.y;
    __syncthreads();
    int tt = threadIdx.x;
    if (tt < 128) {
        float s1 = (sred[0][tt] + sred[1][tt]) + (sred[2][tt] + sred[3][tt]);
        float s2 = (q2red[0][tt] + q2red[1][tt]) + (q2red[2][tt] + q2red[3][tt]);
        atomicAdd(&stats[tt], s1);
        atomicAdd(&stats[128 + tt], s2);
    }
}

// ---------------- fused GATv2 layer 2 + BN stats ----------------
__global__ __launch_bounds__(256) void gat2_fused_kernel(
    const u16* __restrict__ xlp, const float* __restrict__ xr,
    const u32* __restrict__ eah, const int2* __restrict__ pairs,
    const int* __restrict__ rowptr, const float* __restrict__ We,
    const float* __restrict__ att, const float* __restrict__ bias,
    float* __restrict__ out, float* __restrict__ stats)
{
    __shared__ float sred[4][64];
    __shared__ float q2red[4][64];
    int lane = threadIdx.x & 63;
    int d = (blockIdx.x * 256 + threadIdx.x) >> 6;
    int du = __builtin_amdgcn_readfirstlane(d);
    int beg = rowptr[du], end = rowptr[du + 1];
    float w[16];
#pragma unroll
    for (int k = 0; k < 16; ++k) w[k] = We[k * 64 + lane];
    float a0 = att[lane];
    float bb = bias[lane];
    float xrv = xr[(size_t)du * 64 + lane];

    float s = 0.f, acc = 0.f;

    int cnt = (end - beg) >> 2;
    int2 pA[4]; u32 eA[4][8]; float xA[4];
    int2 pB[4]; u32 eB[4][8]; float xB[4];

#define G2_LOAD(P, EB, X, base_) do {                                          \
    _Pragma("unroll")                                                          \
    for (int j = 0; j < 4; ++j) P[j] = pairs[(base_) + j];                     \
    _Pragma("unroll")                                                          \
    for (int j = 0; j < 4; ++j) {                                              \
        const u32* er_ = eah + (size_t)P[j].y * 8;                             \
        _Pragma("unroll")                                                      \
        for (int k = 0; k < 8; ++k) EB[j][k] = er_[k];                         \
        X[j] = uaf((u32)xlp[(size_t)P[j].x * 64 + lane] << 16);                \
    }                                                                          \
} while (0)

#define G2_PROC(EB, X) do {                                                    \
    float q[4];                                                                \
    _Pragma("unroll")                                                          \
    for (int j = 0; j < 4; ++j) {                                              \
        float e = 0.f;                                                         \
        _Pragma("unroll")                                                      \
        for (int kk = 0; kk < 8; ++kk) {                                       \
            u32 pk = EB[j][kk];                                                \
            e = fmaf(uaf(pk << 16), w[2 * kk], e);                             \
            e = fmaf(uaf(pk & 0xffff0000u), w[2 * kk + 1], e);                 \
        }                                                                      \
        float mm = X[j] + xrv + e;                                             \
        mm = fmaxf(mm, 0.2f * mm);                                             \
        q[j] = mm * a0;                                                        \
    }                                                                          \
    RED4_STAGES(q);                                                            \
    _Pragma("unroll")                                                          \
    for (int j = 0; j < 4; ++j) { q[j] = swz_xor16_add(q[j]); q[j] = total64(q[j]); } \
    float w0 = __expf(q[0]), w1 = __expf(q[1]);                                \
    float w2 = __expf(q[2]), w3 = __expf(q[3]);                                \
    s += (w0 + w1) + (w2 + w3);                                                \
    acc += fmaf(w0, X[0], fmaf(w1, X[1], fmaf(w2, X[2], w3 * X[3])));          \
} while (0)

    if (cnt > 0) {
        G2_LOAD(pA, eA, xA, beg);
        int g = 0;
        for (; g + 2 <= cnt; g += 2) {
            G2_LOAD(pB, eB, xB, beg + (g + 1) * 4);
            G2_PROC(eA, xA);
            if (g + 2 < cnt) G2_LOAD(pA, eA, xA, beg + (g + 2) * 4);
            G2_PROC(eB, xB);
        }
        if (g < cnt) G2_PROC(eA, xA);
    }
#undef G2_LOAD
#undef G2_PROC
    for (int i = beg + cnt * 4; i < end; ++i) {
        int2 pr = pairs[i];
        const u32* er = eah + (size_t)pr.y * 8;
        float xv = uaf((u32)xlp[(size_t)pr.x * 64 + lane] << 16);
        float e = 0.f;
#pragma unroll
        for (int kk = 0; kk < 8; ++kk) {
            u32 pk = er[kk];
            e = fmaf(uaf(pk << 16), w[2 * kk], e);
            e = fmaf(uaf(pk & 0xffff0000u), w[2 * kk + 1], e);
        }
        float mm = xv + xrv + e;
        mm = fmaxf(mm, 0.2f * mm);
        float p = mm * a0;
        p = dpp_add<0xB1>(p);
        p = dpp_add<0x4E>(p);
        p = dpp_add<0x141>(p);
        p = dpp_add<0x140>(p);
        p = swz_xor16_add(p);
        p = total64(p);
        float ww = __expf(p);
        s += ww;
        acc = fmaf(ww, xv, acc);
    }
    float o = acc / (s + 1e-16f) + bb;
    out[(size_t)d * 64 + lane] = o;

    int wv = threadIdx.x >> 6;
    sred[wv][lane] = o;
    q2red[wv][lane] = o * o;
    __syncthreads();
    int tt = threadIdx.x;
    if (tt < 64) {
        float s1 = (sred[0][tt] + sred[1][tt]) + (sred[2][tt] + sred[3][tt]);
        float s2 = (q2red[0][tt] + q2red[1][tt]) + (q2red[2][tt] + q2red[3][tt]);
        atomicAdd(&stats[tt], s1);
        atomicAdd(&stats[64 + tt], s2);
    }
}

// ---------------- BN apply + skip + ELU -> packed bf16 ----------------
__global__ __launch_bounds__(256) void bn_apply_pack_kernel(
    const float* __restrict__ h, const float* __restrict__ xp,
    const float* __restrict__ stats, const float* __restrict__ g,
    const float* __restrict__ b, u32* __restrict__ outp)
{
    int i = blockIdx.x * 256 + threadIdx.x;
    if (i >= NN * 64) return;
    int c2 = i & 63;
    int row = i >> 6;
    int c = c2 * 2;
    float2 hv = *(const float2*)(h + (size_t)row * 128 + c);
    float2 xv = *(const float2*)(xp + (size_t)row * 128 + c);
    float mu0 = stats[c] * (1.f / NN);
    float var0 = stats[128 + c] * (1.f / NN) - mu0 * mu0;
    float v0 = (hv.x - mu0) * rsqrtf(var0 + 1e-5f) * g[c] + b[c] + xv.x;
    v0 = (v0 > 0.f) ? v0 : expm1f(v0);
    float mu1 = stats[c + 1] * (1.f / NN);
    float var1 = stats[129 + c] * (1.f / NN) - mu1 * mu1;
    float v1 = (hv.y - mu1) * rsqrtf(var1 + 1e-5f) * g[c + 1] + b[c + 1] + xv.y;
    v1 = (v1 > 0.f) ? v1 : expm1f(v1);
    outp[i] = bfpack2(v0, v1);
}

// ---------------- BN apply + skip + ELU (fp32, final) ----------------
__global__ __launch_bounds__(256) void bn_apply64_kernel(
    const float* __restrict__ h, const float* __restrict__ xp,
    const float* __restrict__ stats, const float* __restrict__ g,
    const float* __restrict__ b, float* __restrict__ outp)
{
    int i = blockIdx.x * 256 + threadIdx.x;
    if (i >= NN * 64) return;
    int c = i & 63;
    float mu = stats[c] * (1.f / NN);
    float var = stats[64 + c] * (1.f / NN) - mu * mu;
    float sc = rsqrtf(var + 1e-5f) * g[c];
    float v = (h[i] - mu) * sc + b[c] + xp[i];
    outp[i] = (v > 0.f) ? v : expm1f(v);
}

// ---------------- pooling + classifier fused ----------------
__global__ __launch_bounds__(256) void pool_cls_kernel(
    const float* __restrict__ h2, const int* __restrict__ batch,
    const float* __restrict__ cw, const float* __restrict__ cb, float* __restrict__ outp)
{
    int g = blockIdx.x;
    int t = threadIdx.x;
    int lane = t & 63, w = t >> 6;
    int lo = 0, hi = NN;
    while (lo < hi) { int mid = (lo + hi) >> 1; if (batch[mid] < g) lo = mid + 1; else hi = mid; }
    int s0 = lo;
    hi = NN;
    while (lo < hi) { int mid = (lo + hi) >> 1; if (batch[mid] < g + 1) lo = mid + 1; else hi = mid; }
    int e0 = lo;
    float sum = 0.f, mx = -INFINITY;
    for (int r = s0 + w; r < e0; r += 4) {
        float v = h2[(size_t)r * 64 + lane];
        sum += v; mx = fmaxf(mx, v);
    }
    __shared__ float lsum[256], lmax[256];
    __shared__ float pm[128];
    lsum[t] = sum; lmax[t] = mx;
    __syncthreads();
    if (w == 0) {
        for (int j = 1; j < 4; ++j) { sum += lsum[j * 64 + lane]; mx = fmaxf(mx, lmax[j * 64 + lane]); }
        float cnt = (float)(e0 - s0);
        pm[lane] = sum / fmaxf(cnt, 1.f);
        pm[64 + lane] = mx;
    }
    __syncthreads();
    if (t < 2) {
        float acc = cb[t];
        for (int k = 0; k < 128; ++k) acc = fmaf(pm[k], cw[k * 2 + t], acc);
        outp[g * 2 + t] = acc;
    }
}

extern "C" void kernel_launch(void* const* d_in, const int* in_sizes, int n_in,
                              void* d_out, int out_size, void* d_ws, size_t ws_size,
                              hipStream_t stream)
{
    const float* x       = (const float*)d_in[0];
    const int*   ei      = (const int*)d_in[1];
    const float* ea      = (const float*)d_in[2];
    const int*   batch   = (const int*)d_in[3];
    const float* skip1_w = (const float*)d_in[4];
    const float* skip1_b = (const float*)d_in[5];
    const float* c1_wl   = (const float*)d_in[6];
    const float* c1_bl   = (const float*)d_in[7];
    const float* c1_wr   = (const float*)d_in[8];
    const float* c1_br   = (const float*)d_in[9];
    const float* c1_we   = (const float*)d_in[10];
    const float* c1_att  = (const float*)d_in[11];
    const float* c1_bias = (const float*)d_in[12];
    const float* bn1_g   = (const float*)d_in[13];
    const float* bn1_b   = (const float*)d_in[14];
    const float* skip2_w = (const float*)d_in[15];
    const float* skip2_b = (const float*)d_in[16];
    const float* c2_wl   = (const float*)d_in[17];
    const float* c2_bl   = (const float*)d_in[18];
    const float* c2_wr   = (const float*)d_in[19];
    const float* c2_br   = (const float*)d_in[20];
    const float* c2_we   = (const float*)d_in[21];
    const float* c2_att  = (const float*)d_in[22];
    const float* c2_bias = (const float*)d_in[23];
    const float* bn2_g   = (const float*)d_in[24];
    const float* bn2_b   = (const float*)d_in[25];
    const float* cls_w   = (const float*)d_in[26];
    const float* cls_b   = (const float*)d_in[27];
    float* outp = (float*)d_out;

    float* ws = (float*)d_ws;
    size_t o = 0;
    float* A   = ws + o; o += 6400000;   // XL1P bf16 [n][128]; layer2: XL2P bf16 (lower) + xr2 fp32 (upper)
    float* B   = ws + o; o += 6400000;   // xr1 fp32 [n][128]
    float* Cb  = ws + o; o += 6400000;   // xp1 fp32 ; later xp2 (lower) + h2 final (upper)
    float* D   = ws + o; o += 6400000;   // h1 pre-BN [n][128] ; later h2 pre-BN [n][64]
    int2*  PAIRS = (int2*)(ws + o); o += 1600000;
    u32*   EAH   = (u32*)(ws + o); o += 6400000;   // ea packed bf16 [E][8]
    u32*   XP    = (u32*)(ws + o); o += 3200000;   // x packed bf16 [n][64] ; later h packed
    u32*   WT1   = (u32*)(ws + o); o += 24576;     // [384][64]
    u32*   WT2   = (u32*)(ws + o); o += 12288;     // [192][64]
    u32*   COUNTS  = (u32*)(ws + o); o += 50000;   // --- zeroed region start (100384 u32)
    u32*   CURSORS = (u32*)(ws + o); o += 50000;
    float* STATS1  = ws + o; o += 256;
    float* STATS2  = ws + o; o += 128;             // --- zeroed region end
    int*   ROWPTR  = (int*)(ws + o); o += 50016;

    u16*   XL1P = (u16*)A;
    u16*   XL2P = (u16*)A;
    float* xr2  = A + 3200000;
    float* xp2  = Cb;
    float* h2   = Cb + 3200000;

    // 1: zeros + ea pack + x pack + weight packs
    pre_kernel<<<(PRE_TOT + 255) / 256, 256, 0, stream>>>(
        ea, x, c1_wl, c1_wr, skip1_w, c2_wl, c2_wr, skip2_w,
        COUNTS, EAH, XP, WT1, WT2);
    // 2: CSR count
    count_edges_kernel<<<(NE + 255) / 256, 256, 0, stream>>>(ei, COUNTS);
    // 3: full scan (one block)
    scan_kernel<<<1, 1024, 0, stream>>>(COUNTS, ROWPTR);
    // 4: scatter + layer-1 GEMM
    scatter_gemm1_kernel<<<3125 + 782 * 6, 256, 0, stream>>>(
        ei, ROWPTR, CURSORS, PAIRS, XP, WT1,
        XL1P, B, Cb, c1_bl, c1_br, skip1_b);
    // 5: GAT layer 1 + BN1 stats
    gat1_fused_kernel<<<NN / 4, 256, 0, stream>>>((const u32*)XL1P, B, EAH, PAIRS, ROWPTR,
                                                  c1_we, c1_att, c1_bias, D, STATS1);
    // 6: BN1 apply + skip + ELU -> packed bf16
    bn_apply_pack_kernel<<<(NN * 64 + 255) / 256, 256, 0, stream>>>(D, Cb, STATS1, bn1_g, bn1_b, XP);
    // 7: layer-2 GEMM
    gemm_mfma_kernel<<<dim3(782, 3), 256, 0, stream>>>(XP, WT2, XL2P, xr2, xp2, c2_bl, c2_br, skip2_b);
    // 8: GAT layer 2 + BN2 stats
    gat2_fused_kernel<<<NN / 4, 256, 0, stream>>>(XL2P, xr2, EAH, PAIRS, ROWPTR,
                                                  c2_we, c2_att, c2_bias, D, STATS2);
    // 9: BN2 apply + skip + ELU
    bn_apply64_kernel<<<(NN * 64 + 255) / 256, 256, 0, stream>>>(D, xp2, STATS2, bn2_g, bn2_b, h2);
    // 10: pool + classifier
    pool_cls_kernel<<<GG, 256, 0, stream>>>(h2, batch, cls_w, cls_b, outp);
}

// Round 11
// 697.994 us; speedup vs baseline: 1.5516x; 1.5516x over previous
//
#include <hip/hip_runtime.h>
#include <math.h>

#define NN 50000
#define NE 800000
#define GG 50

typedef unsigned int u32;
typedef unsigned short u16;
typedef float v2f __attribute__((ext_vector_type(2)));
typedef short bf16x8 __attribute__((ext_vector_type(8)));
typedef float f32x4 __attribute__((ext_vector_type(4)));

__device__ __forceinline__ float uaf(u32 x) { return __uint_as_float(x); }

__device__ __forceinline__ u32 bfpack2(float x, float y) {
    u32 a = __float_as_uint(x), b = __float_as_uint(y);
    a = (a + 0x7fffu + ((a >> 16) & 1u)) >> 16;
    b = (b + 0x7fffu + ((b >> 16) & 1u)) & 0xffff0000u;
    return b | a;
}
__device__ __forceinline__ u16 bf16of(float x) {
    u32 a = __float_as_uint(x);
    return (u16)((a + 0x7fffu + ((a >> 16) & 1u)) >> 16);
}

template <int CTRL>
__device__ __forceinline__ float dpp_add(float v) {
    int t = __builtin_amdgcn_update_dpp(0, __float_as_int(v), CTRL, 0xf, 0xf, true);
    return v + __int_as_float(t);
}
__device__ __forceinline__ float swz_xor16_add(float v) {
    int t = __builtin_amdgcn_ds_swizzle(__float_as_int(v), 0x401F);
    return v + __int_as_float(t);
}
__device__ __forceinline__ float total64(float v) {
    return __int_as_float(__builtin_amdgcn_readlane(__float_as_int(v), 0))
         + __int_as_float(__builtin_amdgcn_readlane(__float_as_int(v), 32));
}
#define RED4_STAGES(q)  do {                                                    \
    _Pragma("unroll") for (int j = 0; j < 4; ++j) q[j] = dpp_add<0xB1>(q[j]);  \
    _Pragma("unroll") for (int j = 0; j < 4; ++j) q[j] = dpp_add<0x4E>(q[j]);  \
    _Pragma("unroll") for (int j = 0; j < 4; ++j) q[j] = dpp_add<0x141>(q[j]); \
    _Pragma("unroll") for (int j = 0; j < 4; ++j) q[j] = dpp_add<0x140>(q[j]); \
} while (0)

// ---------------- mega pre-kernel: zeros + ea pack + x pack + weight packs ----------------
#define PRE_ZERO 100384
#define PRE_EA   (PRE_ZERO + 6400000)
#define PRE_XP   (PRE_EA + 3200000)
#define PRE_W1   (PRE_XP + 24576)
#define PRE_W2   (PRE_W1 + 12288)
#define PRE_TOT  PRE_W2

__device__ __forceinline__ void wpack_item(const float* __restrict__ W0, const float* __restrict__ W1,
                                           const float* __restrict__ W2, u32* __restrict__ Wt, int M, int j) {
    int per = M * 64;
    int mat = j / per;
    int r = j - mat * per;
    const float* W = (mat == 0) ? W0 : (mat == 1) ? W1 : W2;
    int col = r >> 6, c = r & 63;
    Wt[j] = bfpack2(W[(size_t)(2 * c) * M + col], W[(size_t)(2 * c + 1) * M + col]);
}

__global__ __launch_bounds__(256) void pre_kernel(
    const float* __restrict__ ea, const float* __restrict__ x,
    const float* __restrict__ w1a, const float* __restrict__ w1b, const float* __restrict__ w1c,
    const float* __restrict__ w2a, const float* __restrict__ w2b, const float* __restrict__ w2c,
    u32* __restrict__ zbase, u32* __restrict__ eah, u32* __restrict__ xp,
    u32* __restrict__ wt1, u32* __restrict__ wt2)
{
    int i = blockIdx.x * 256 + threadIdx.x;
    if (i < PRE_ZERO) {
        zbase[i] = 0u;
    } else if (i < PRE_EA) {
        int j = i - PRE_ZERO;
        float2 v = *(const float2*)(ea + (size_t)j * 2);
        eah[j] = bfpack2(v.x, v.y);
    } else if (i < PRE_XP) {
        int j = i - PRE_EA;
        float2 v = *(const float2*)(x + (size_t)j * 2);
        xp[j] = bfpack2(v.x, v.y);
    } else if (i < PRE_W1) {
        wpack_item(w1a, w1b, w1c, wt1, 128, i - PRE_XP);
    } else if (i < PRE_W2) {
        wpack_item(w2a, w2b, w2c, wt2, 64, i - PRE_W1);
    }
}

// ---------------- CSR: count ----------------
__global__ void count_edges_kernel(const int* __restrict__ ei, u32* __restrict__ counts) {
    int e = blockIdx.x * 256 + threadIdx.x;
    if (e < NE) atomicAdd(&counts[ei[NE + e]], 1u);
}

// ---------------- CSR: single-block full scan ----------------
__global__ __launch_bounds__(1024) void scan_kernel(const u32* __restrict__ counts, int* __restrict__ rowptr) {
    __shared__ u32 ts[1024];
    int t = threadIdx.x;
    int base = t * 49;
    u32 c[49];
    u32 s = 0;
#pragma unroll
    for (int j = 0; j < 49; ++j) {
        int idx = base + j;
        c[j] = (idx < NN) ? counts[idx] : 0u;
        s += c[j];
    }
    ts[t] = s;
    __syncthreads();
    for (int off = 1; off < 1024; off <<= 1) {
        u32 add = (t >= off) ? ts[t - off] : 0u;
        __syncthreads();
        ts[t] += add;
        __syncthreads();
    }
    u32 run = ts[t] - s;
#pragma unroll
    for (int j = 0; j < 49; ++j) {
        int idx = base + j;
        if (idx < NN) rowptr[idx] = (int)run;
        run += c[j];
    }
    if (t == 1023) rowptr[NN] = NE;
}

// ---------------- merged: scatter (blocks 0..3124) + layer-1 MFMA GEMM (rest) ----------------
__global__ __launch_bounds__(256) void scatter_gemm1_kernel(
    const int* __restrict__ ei, const int* __restrict__ rowptr,
    u32* __restrict__ cursors, int2* __restrict__ pairs,
    const u32* __restrict__ Xp, const u32* __restrict__ Wt,
    u16* __restrict__ out0, float* __restrict__ out1, float* __restrict__ out2,
    const float* __restrict__ b0, const float* __restrict__ b1, const float* __restrict__ b2)
{
    __shared__ __align__(16) u32 Xs[64 * 68];
    __shared__ __align__(16) u32 Ws[64 * 68];
    int t = threadIdx.x;

    if (blockIdx.x < 3125) {                       // scatter part
        int e = blockIdx.x * 256 + t;
        if (e < NE) {
            int src = ei[e];
            int d = ei[NE + e];
            u32 pos = atomicAdd(&cursors[d], 1u);
            pairs[rowptr[d] + pos] = make_int2(src, e);
        }
        return;
    }
    int bid = blockIdx.x - 3125;                   // gemm part: 782*6 blocks
    int nb = bid / 782;
    int rowb = bid - nb * 782;
    int row0 = rowb * 64;
    int mat = nb >> 1;                             // nbPerMat = 2
    int col0 = (nb & 1) * 64;
    int gcol0 = nb * 64;

#pragma unroll
    for (int i = 0; i < 16; ++i) {
        int flat = t + 256 * i;
        int r = flat >> 6, c = flat & 63;
        int gr = row0 + r;
        u32 v = (gr < NN) ? Xp[(size_t)gr * 64 + c] : 0u;
        Xs[r * 68 + c] = v;
    }
#pragma unroll
    for (int i = 0; i < 16; ++i) {
        int flat = t + 256 * i;
        int cc = flat >> 6, c = flat & 63;
        Ws[cc * 68 + c] = Wt[(size_t)(gcol0 + cc) * 64 + c];
    }
    __syncthreads();

    int w = t >> 6, lane = t & 63;
    int l15 = lane & 15, quad = lane >> 4;
    f32x4 acc[4] = {};
#pragma unroll
    for (int kk = 0; kk < 4; ++kk) {
        bf16x8 af = *(const bf16x8*)&Xs[(w * 16 + l15) * 68 + kk * 16 + quad * 4];
#pragma unroll
        for (int j = 0; j < 4; ++j) {
            bf16x8 bf = *(const bf16x8*)&Ws[(j * 16 + l15) * 68 + kk * 16 + quad * 4];
            acc[j] = __builtin_amdgcn_mfma_f32_16x16x32_bf16(af, bf, acc[j], 0, 0, 0);
        }
    }
    const float* bp = (mat == 0) ? b0 : (mat == 1) ? b1 : b2;
#pragma unroll
    for (int j = 0; j < 4; ++j) {
        int col = col0 + j * 16 + l15;
        float bb = bp[col];
#pragma unroll
        for (int r = 0; r < 4; ++r) {
            int grow = row0 + w * 16 + quad * 4 + r;
            if (grow < NN) {
                float v = acc[j][r] + bb;
                if (mat == 0)      out0[(size_t)grow * 128 + col] = bf16of(v);
                else if (mat == 1) out1[(size_t)grow * 128 + col] = v;
                else               out2[(size_t)grow * 128 + col] = v;
            }
        }
    }
}

// ---------------- layer-2 MFMA GEMM ----------------
__global__ __launch_bounds__(256) void gemm_mfma_kernel(
    const u32* __restrict__ Xp, const u32* __restrict__ Wt,
    u16* __restrict__ out0, float* __restrict__ out1, float* __restrict__ out2,
    const float* __restrict__ b0, const float* __restrict__ b1, const float* __restrict__ b2)
{
    __shared__ __align__(16) u32 Xs[64 * 68];
    __shared__ __align__(16) u32 Ws[64 * 68];
    int t = threadIdx.x;
    int row0 = blockIdx.x * 64;
    int nb = blockIdx.y;          // 0..2, M = 64
    int mat = nb;
    int gcol0 = nb * 64;

#pragma unroll
    for (int i = 0; i < 16; ++i) {
        int flat = t + 256 * i;
        int r = flat >> 6, c = flat & 63;
        int gr = row0 + r;
        u32 v = (gr < NN) ? Xp[(size_t)gr * 64 + c] : 0u;
        Xs[r * 68 + c] = v;
    }
#pragma unroll
    for (int i = 0; i < 16; ++i) {
        int flat = t + 256 * i;
        int cc = flat >> 6, c = flat & 63;
        Ws[cc * 68 + c] = Wt[(size_t)(gcol0 + cc) * 64 + c];
    }
    __syncthreads();

    int w = t >> 6, lane = t & 63;
    int l15 = lane & 15, quad = lane >> 4;
    f32x4 acc[4] = {};
#pragma unroll
    for (int kk = 0; kk < 4; ++kk) {
        bf16x8 af = *(const bf16x8*)&Xs[(w * 16 + l15) * 68 + kk * 16 + quad * 4];
#pragma unroll
        for (int j = 0; j < 4; ++j) {
            bf16x8 bf = *(const bf16x8*)&Ws[(j * 16 + l15) * 68 + kk * 16 + quad * 4];
            acc[j] = __builtin_amdgcn_mfma_f32_16x16x32_bf16(af, bf, acc[j], 0, 0, 0);
        }
    }
    const float* bp = (mat == 0) ? b0 : (mat == 1) ? b1 : b2;
#pragma unroll
    for (int j = 0; j < 4; ++j) {
        int col = j * 16 + l15;
        float bb = bp[col];
#pragma unroll
        for (int r = 0; r < 4; ++r) {
            int grow = row0 + w * 16 + quad * 4 + r;
            if (grow < NN) {
                float v = acc[j][r] + bb;
                if (mat == 0)      out0[(size_t)grow * 64 + col] = bf16of(v);
                else if (mat == 1) out1[(size_t)grow * 64 + col] = v;
                else               out2[(size_t)grow * 64 + col] = v;
            }
        }
    }
}

// ---------------- fused GATv2 layer 1 (R9 version: no stats epilogue) ----------------
__global__ __launch_bounds__(256) void gat1_fused_kernel(
    const u32* __restrict__ xlp, const float* __restrict__ xr,
    const u32* __restrict__ eah, const int2* __restrict__ pairs,
    const int* __restrict__ rowptr, const float* __restrict__ We,
    const float* __restrict__ att, const float* __restrict__ bias,
    float* __restrict__ out)
{
    int lane = threadIdx.x & 63;
    int d = (blockIdx.x * 256 + threadIdx.x) >> 6;
    if (d >= NN) return;
    int du = __builtin_amdgcn_readfirstlane(d);
    int beg = rowptr[du], end = rowptr[du + 1];
    int c0 = lane * 2;
    v2f w[16];
#pragma unroll
    for (int k = 0; k < 16; ++k) {
        float2 t2 = *(const float2*)(We + k * 128 + c0);
        w[k] = (v2f){t2.x, t2.y};
    }
    float a0 = att[c0], a1 = att[c0 + 1];
    float2 bt = *(const float2*)(bias + c0);
    float2 xq = *(const float2*)(xr + (size_t)du * 128 + c0);
    v2f xrv = {xq.x, xq.y};

    float s = 0.f;
    v2f acc = {0.f, 0.f};

    int cnt = (end - beg) >> 2;
    int2 pA[4]; u32 eA[4][8]; u32 xA[4];
    int2 pB[4]; u32 eB[4][8]; u32 xB[4];

#define G1_LOAD(P, EB, X, base_) do {                                          \
    _Pragma("unroll")                                                          \
    for (int j = 0; j < 4; ++j) P[j] = pairs[(base_) + j];                     \
    _Pragma("unroll")                                                          \
    for (int j = 0; j < 4; ++j) {                                              \
        const u32* er_ = eah + (size_t)P[j].y * 8;                             \
        _Pragma("unroll")                                                      \
        for (int k = 0; k < 8; ++k) EB[j][k] = er_[k];                         \
        X[j] = xlp[(size_t)P[j].x * 64 + lane];                                \
    }                                                                          \
} while (0)

#define G1_PROC(EB, X) do {                                                    \
    float q[4]; v2f xv[4];                                                     \
    _Pragma("unroll")                                                          \
    for (int j = 0; j < 4; ++j) {                                              \
        v2f e = {0.f, 0.f};                                                    \
        _Pragma("unroll")                                                      \
        for (int kk = 0; kk < 8; ++kk) {                                       \
            u32 pk = EB[j][kk];                                                \
            e = w[2 * kk] * uaf(pk << 16) + e;                                 \
            e = w[2 * kk + 1] * uaf(pk & 0xffff0000u) + e;                     \
        }                                                                      \
        u32 px = X[j];                                                         \
        xv[j] = (v2f){uaf(px << 16), uaf(px & 0xffff0000u)};                   \
        v2f mm = xv[j] + xrv + e;                                              \
        float lx = fmaxf(mm.x, 0.2f * mm.x);                                   \
        float ly = fmaxf(mm.y, 0.2f * mm.y);                                   \
        q[j] = fmaf(lx, a0, ly * a1);                                          \
    }                                                                          \
    RED4_STAGES(q);                                                            \
    _Pragma("unroll")                                                          \
    for (int j = 0; j < 4; ++j) q[j] = swz_xor16_add(q[j]);                    \
    float w0 = __expf(q[0]), w1 = __expf(q[1]);                                \
    float w2 = __expf(q[2]), w3 = __expf(q[3]);                                \
    s += (w0 + w1) + (w2 + w3);                                                \
    acc = acc + (xv[0] * w0 + xv[1] * w1) + (xv[2] * w2 + xv[3] * w3);         \
} while (0)

    if (cnt > 0) {
        G1_LOAD(pA, eA, xA, beg);
        int g = 0;
        for (; g + 2 <= cnt; g += 2) {
            G1_LOAD(pB, eB, xB, beg + (g + 1) * 4);
            G1_PROC(eA, xA);
            if (g + 2 < cnt) G1_LOAD(pA, eA, xA, beg + (g + 2) * 4);
            G1_PROC(eB, xB);
        }
        if (g < cnt) G1_PROC(eA, xA);
    }
#undef G1_LOAD
#undef G1_PROC
    for (int i = beg + cnt * 4; i < end; ++i) {
        int2 pr = pairs[i];
        const u32* er = eah + (size_t)pr.y * 8;
        u32 px = xlp[(size_t)pr.x * 64 + lane];
        v2f xv = {uaf(px << 16), uaf(px & 0xffff0000u)};
        v2f e = {0.f, 0.f};
#pragma unroll
        for (int kk = 0; kk < 8; ++kk) {
            u32 pk = er[kk];
            e = w[2 * kk] * uaf(pk << 16) + e;
            e = w[2 * kk + 1] * uaf(pk & 0xffff0000u) + e;
        }
        v2f mm = xv + xrv + e;
        float lx = fmaxf(mm.x, 0.2f * mm.x);
        float ly = fmaxf(mm.y, 0.2f * mm.y);
        float p = fmaf(lx, a0, ly * a1);
        p = dpp_add<0xB1>(p);
        p = dpp_add<0x4E>(p);
        p = dpp_add<0x141>(p);
        p = dpp_add<0x140>(p);
        p = swz_xor16_add(p);
        float ww = __expf(p);
        s += ww;
        acc = acc + xv * ww;
    }
    float inv = 1.f / (s + 1e-16f);
    float2 o;
    o.x = fmaf(acc.x, inv, bt.x);
    o.y = fmaf(acc.y, inv, bt.y);
    *(float2*)(out + (size_t)d * 128 + c0) = o;
}

// ---------------- fused GATv2 layer 2 (R9 version) ----------------
__global__ __launch_bounds__(256) void gat2_fused_kernel(
    const u16* __restrict__ xlp, const float* __restrict__ xr,
    const u32* __restrict__ eah, const int2* __restrict__ pairs,
    const int* __restrict__ rowptr, const float* __restrict__ We,
    const float* __restrict__ att, const float* __restrict__ bias,
    float* __restrict__ out)
{
    int lane = threadIdx.x & 63;
    int d = (blockIdx.x * 256 + threadIdx.x) >> 6;
    if (d >= NN) return;
    int du = __builtin_amdgcn_readfirstlane(d);
    int beg = rowptr[du], end = rowptr[du + 1];
    float w[16];
#pragma unroll
    for (int k = 0; k < 16; ++k) w[k] = We[k * 64 + lane];
    float a0 = att[lane];
    float bb = bias[lane];
    float xrv = xr[(size_t)du * 64 + lane];

    float s = 0.f, acc = 0.f;

    int cnt = (end - beg) >> 2;
    int2 pA[4]; u32 eA[4][8]; float xA[4];
    int2 pB[4]; u32 eB[4][8]; float xB[4];

#define G2_LOAD(P, EB, X, base_) do {                                          \
    _Pragma("unroll")                                                          \
    for (int j = 0; j < 4; ++j) P[j] = pairs[(base_) + j];                     \
    _Pragma("unroll")                                                          \
    for (int j = 0; j < 4; ++j) {                                              \
        const u32* er_ = eah + (size_t)P[j].y * 8;                             \
        _Pragma("unroll")                                                      \
        for (int k = 0; k < 8; ++k) EB[j][k] = er_[k];                         \
        X[j] = uaf((u32)xlp[(size_t)P[j].x * 64 + lane] << 16);                \
    }                                                                          \
} while (0)

#define G2_PROC(EB, X) do {                                                    \
    float q[4];                                                                \
    _Pragma("unroll")                                                          \
    for (int j = 0; j < 4; ++j) {                                              \
        float e = 0.f;                                                         \
        _Pragma("unroll")                                                      \
        for (int kk = 0; kk < 8; ++kk) {                                       \
            u32 pk = EB[j][kk];                                                \
            e = fmaf(uaf(pk << 16), w[2 * kk], e);                             \
            e = fmaf(uaf(pk & 0xffff0000u), w[2 * kk + 1], e);                 \
        }                                                                      \
        float mm = X[j] + xrv + e;                                             \
        mm = fmaxf(mm, 0.2f * mm);                                             \
        q[j] = mm * a0;                                                        \
    }                                                                          \
    RED4_STAGES(q);                                                            \
    _Pragma("unroll")                                                          \
    for (int j = 0; j < 4; ++j) { q[j] = swz_xor16_add(q[j]); q[j] = total64(q[j]); } \
    float w0 = __expf(q[0]), w1 = __expf(q[1]);                                \
    float w2 = __expf(q[2]), w3 = __expf(q[3]);                                \
    s += (w0 + w1) + (w2 + w3);                                                \
    acc += fmaf(w0, X[0], fmaf(w1, X[1], fmaf(w2, X[2], w3 * X[3])));          \
} while (0)

    if (cnt > 0) {
        G2_LOAD(pA, eA, xA, beg);
        int g = 0;
        for (; g + 2 <= cnt; g += 2) {
            G2_LOAD(pB, eB, xB, beg + (g + 1) * 4);
            G2_PROC(eA, xA);
            if (g + 2 < cnt) G2_LOAD(pA, eA, xA, beg + (g + 2) * 4);
            G2_PROC(eB, xB);
        }
        if (g < cnt) G2_PROC(eA, xA);
    }
#undef G2_LOAD
#undef G2_PROC
    for (int i = beg + cnt * 4; i < end; ++i) {
        int2 pr = pairs[i];
        const u32* er = eah + (size_t)pr.y * 8;
        float xv = uaf((u32)xlp[(size_t)pr.x * 64 + lane] << 16);
        float e = 0.f;
#pragma unroll
        for (int kk = 0; kk < 8; ++kk) {
            u32 pk = er[kk];
            e = fmaf(uaf(pk << 16), w[2 * kk], e);
            e = fmaf(uaf(pk & 0xffff0000u), w[2 * kk + 1], e);
        }
        float mm = xv + xrv + e;
        mm = fmaxf(mm, 0.2f * mm);
        float p = mm * a0;
        p = dpp_add<0xB1>(p);
        p = dpp_add<0x4E>(p);
        p = dpp_add<0x141>(p);
        p = dpp_add<0x140>(p);
        p = swz_xor16_add(p);
        p = total64(p);
        float ww = __expf(p);
        s += ww;
        acc = fmaf(ww, xv, acc);
    }
    out[(size_t)d * 64 + lane] = acc / (s + 1e-16f) + bb;
}

// ---------------- batch-norm stats (98 blocks -> low atomic contention) ----------------
template <int C>
__global__ __launch_bounds__(256) void bn_stats_kernel(const float* __restrict__ h, float* __restrict__ stats) {
    const int SUB = 256 / C;
    int t = threadIdx.x;
    int c = t & (C - 1);
    int rs = t / C;
    int r0 = blockIdx.x * 512;
    int r1 = min(NN, r0 + 512);
    float s = 0.f, s2 = 0.f;
    for (int r = r0 + rs; r < r1; r += SUB) {
        float v = h[(size_t)r * C + c];
        s += v; s2 = fmaf(v, v, s2);
    }
    __shared__ float ls[256], ls2[256];
    ls[t] = s; ls2[t] = s2;
    __syncthreads();
    if (rs == 0) {
        for (int j = 1; j < SUB; ++j) { s += ls[j * C + c]; s2 += ls2[j * C + c]; }
        atomicAdd(&stats[c], s);
        atomicAdd(&stats[C + c], s2);
    }
}

// ---------------- BN apply + skip + ELU -> packed bf16 ----------------
__global__ __launch_bounds__(256) void bn_apply_pack_kernel(
    const float* __restrict__ h, const float* __restrict__ xp,
    const float* __restrict__ stats, const float* __restrict__ g,
    const float* __restrict__ b, u32* __restrict__ outp)
{
    int i = blockIdx.x * 256 + threadIdx.x;
    if (i >= NN * 64) return;
    int c2 = i & 63;
    int row = i >> 6;
    int c = c2 * 2;
    float2 hv = *(const float2*)(h + (size_t)row * 128 + c);
    float2 xv = *(const float2*)(xp + (size_t)row * 128 + c);
    float mu0 = stats[c] * (1.f / NN);
    float var0 = stats[128 + c] * (1.f / NN) - mu0 * mu0;
    float v0 = (hv.x - mu0) * rsqrtf(var0 + 1e-5f) * g[c] + b[c] + xv.x;
    v0 = (v0 > 0.f) ? v0 : expm1f(v0);
    float mu1 = stats[c + 1] * (1.f / NN);
    float var1 = stats[129 + c] * (1.f / NN) - mu1 * mu1;
    float v1 = (hv.y - mu1) * rsqrtf(var1 + 1e-5f) * g[c + 1] + b[c + 1] + xv.y;
    v1 = (v1 > 0.f) ? v1 : expm1f(v1);
    outp[i] = bfpack2(v0, v1);
}

// ---------------- BN apply + skip + ELU (fp32, final) ----------------
__global__ __launch_bounds__(256) void bn_apply64_kernel(
    const float* __restrict__ h, const float* __restrict__ xp,
    const float* __restrict__ stats, const float* __restrict__ g,
    const float* __restrict__ b, float* __restrict__ outp)
{
    int i = blockIdx.x * 256 + threadIdx.x;
    if (i >= NN * 64) return;
    int c = i & 63;
    float mu = stats[c] * (1.f / NN);
    float var = stats[64 + c] * (1.f / NN) - mu * mu;
    float sc = rsqrtf(var + 1e-5f) * g[c];
    float v = (h[i] - mu) * sc + b[c] + xp[i];
    outp[i] = (v > 0.f) ? v : expm1f(v);
}

// ---------------- pooling + classifier fused ----------------
__global__ __launch_bounds__(256) void pool_cls_kernel(
    const float* __restrict__ h2, const int* __restrict__ batch,
    const float* __restrict__ cw, const float* __restrict__ cb, float* __restrict__ outp)
{
    int g = blockIdx.x;
    int t = threadIdx.x;
    int lane = t & 63, w = t >> 6;
    int lo = 0, hi = NN;
    while (lo < hi) { int mid = (lo + hi) >> 1; if (batch[mid] < g) lo = mid + 1; else hi = mid; }
    int s0 = lo;
    hi = NN;
    while (lo < hi) { int mid = (lo + hi) >> 1; if (batch[mid] < g + 1) lo = mid + 1; else hi = mid; }
    int e0 = lo;
    float sum = 0.f, mx = -INFINITY;
    for (int r = s0 + w; r < e0; r += 4) {
        float v = h2[(size_t)r * 64 + lane];
        sum += v; mx = fmaxf(mx, v);
    }
    __shared__ float lsum[256], lmax[256];
    __shared__ float pm[128];
    lsum[t] = sum; lmax[t] = mx;
    __syncthreads();
    if (w == 0) {
        for (int j = 1; j < 4; ++j) { sum += lsum[j * 64 + lane]; mx = fmaxf(mx, lmax[j * 64 + lane]); }
        float cnt = (float)(e0 - s0);
        pm[lane] = sum / fmaxf(cnt, 1.f);
        pm[64 + lane] = mx;
    }
    __syncthreads();
    if (t < 2) {
        float acc = cb[t];
        for (int k = 0; k < 128; ++k) acc = fmaf(pm[k], cw[k * 2 + t], acc);
        outp[g * 2 + t] = acc;
    }
}

extern "C" void kernel_launch(void* const* d_in, const int* in_sizes, int n_in,
                              void* d_out, int out_size, void* d_ws, size_t ws_size,
                              hipStream_t stream)
{
    const float* x       = (const float*)d_in[0];
    const int*   ei      = (const int*)d_in[1];
    const float* ea      = (const float*)d_in[2];
    const int*   batch   = (const int*)d_in[3];
    const float* skip1_w = (const float*)d_in[4];
    const float* skip1_b = (const float*)d_in[5];
    const float* c1_wl   = (const float*)d_in[6];
    const float* c1_bl   = (const float*)d_in[7];
    const float* c1_wr   = (const float*)d_in[8];
    const float* c1_br   = (const float*)d_in[9];
    const float* c1_we   = (const float*)d_in[10];
    const float* c1_att  = (const float*)d_in[11];
    const float* c1_bias = (const float*)d_in[12];
    const float* bn1_g   = (const float*)d_in[13];
    const float* bn1_b   = (const float*)d_in[14];
    const float* skip2_w = (const float*)d_in[15];
    const float* skip2_b = (const float*)d_in[16];
    const float* c2_wl   = (const float*)d_in[17];
    const float* c2_bl   = (const float*)d_in[18];
    const float* c2_wr   = (const float*)d_in[19];
    const float* c2_br   = (const float*)d_in[20];
    const float* c2_we   = (const float*)d_in[21];
    const float* c2_att  = (const float*)d_in[22];
    const float* c2_bias = (const float*)d_in[23];
    const float* bn2_g   = (const float*)d_in[24];
    const float* bn2_b   = (const float*)d_in[25];
    const float* cls_w   = (const float*)d_in[26];
    const float* cls_b   = (const float*)d_in[27];
    float* outp = (float*)d_out;

    float* ws = (float*)d_ws;
    size_t o = 0;
    float* A   = ws + o; o += 6400000;   // XL1P bf16 [n][128]; layer2: XL2P bf16 (lower) + xr2 fp32 (upper)
    float* B   = ws + o; o += 6400000;   // xr1 fp32 [n][128]
    float* Cb  = ws + o; o += 6400000;   // xp1 fp32 ; later xp2 (lower) + h2 final (upper)
    float* D   = ws + o; o += 6400000;   // h1 pre-BN [n][128] ; later h2 pre-BN [n][64]
    int2*  PAIRS = (int2*)(ws + o); o += 1600000;
    u32*   EAH   = (u32*)(ws + o); o += 6400000;   // ea packed bf16 [E][8]
    u32*   XP    = (u32*)(ws + o); o += 3200000;   // x packed bf16 [n][64] ; later h packed
    u32*   WT1   = (u32*)(ws + o); o += 24576;     // [384][64]
    u32*   WT2   = (u32*)(ws + o); o += 12288;     // [192][64]
    u32*   COUNTS  = (u32*)(ws + o); o += 50000;   // --- zeroed region (100384 u32)
    u32*   CURSORS = (u32*)(ws + o); o += 50000;
    float* STATS1  = ws + o; o += 256;
    float* STATS2  = ws + o; o += 128;             // --- zeroed region end
    int*   ROWPTR  = (int*)(ws + o); o += 50016;

    u16*   XL1P = (u16*)A;
    u16*   XL2P = (u16*)A;
    float* xr2  = A + 3200000;
    float* xp2  = Cb;
    float* h2   = Cb + 3200000;

    // 1: zeros + ea pack + x pack + weight packs
    pre_kernel<<<(PRE_TOT + 255) / 256, 256, 0, stream>>>(
        ea, x, c1_wl, c1_wr, skip1_w, c2_wl, c2_wr, skip2_w,
        COUNTS, EAH, XP, WT1, WT2);
    // 2: CSR count
    count_edges_kernel<<<(NE + 255) / 256, 256, 0, stream>>>(ei, COUNTS);
    // 3: full scan (one block)
    scan_kernel<<<1, 1024, 0, stream>>>(COUNTS, ROWPTR);
    // 4: scatter + layer-1 GEMM
    scatter_gemm1_kernel<<<3125 + 782 * 6, 256, 0, stream>>>(
        ei, ROWPTR, CURSORS, PAIRS, XP, WT1,
        XL1P, B, Cb, c1_bl, c1_br, skip1_b);
    // 5: GAT layer 1
    gat1_fused_kernel<<<NN / 4, 256, 0, stream>>>((const u32*)XL1P, B, EAH, PAIRS, ROWPTR,
                                                  c1_we, c1_att, c1_bias, D);
    // 6: BN1 stats (98 blocks)
    bn_stats_kernel<128><<<98, 256, 0, stream>>>(D, STATS1);
    // 7: BN1 apply + skip + ELU -> packed bf16
    bn_apply_pack_kernel<<<(NN * 64 + 255) / 256, 256, 0, stream>>>(D, Cb, STATS1, bn1_g, bn1_b, XP);
    // 8: layer-2 GEMM
    gemm_mfma_kernel<<<dim3(782, 3), 256, 0, stream>>>(XP, WT2, XL2P, xr2, xp2, c2_bl, c2_br, skip2_b);
    // 9: GAT layer 2
    gat2_fused_kernel<<<NN / 4, 256, 0, stream>>>(XL2P, xr2, EAH, PAIRS, ROWPTR,
                                                  c2_we, c2_att, c2_bias, D);
    // 10: BN2 stats
    bn_stats_kernel<64><<<98, 256, 0, stream>>>(D, STATS2);
    // 11: BN2 apply + skip + ELU
    bn_apply64_kernel<<<(NN * 64 + 255) / 256, 256, 0, stream>>>(D, xp2, STATS2, bn2_g, bn2_b, h2);
    // 12: pool + classifier
    pool_cls_kernel<<<GG, 256, 0, stream>>>(h2, batch, cls_w, cls_b, outp);
}